// Round 12
// baseline (371.442 us; speedup 1.0000x reference)
//
#include <hip/hip_runtime.h>
#include <hip/hip_bf16.h>
#include <math.h>

#define B_ 2
#define L_ 2048
#define D_ 1024
#define QH_ 8
#define KVH_ 2
#define HD_ 128
#define FFN_ 4096
#define T_ (B_ * L_)
#define EPS_ 1.1920929e-07f

typedef __bf16 bf16x8 __attribute__((ext_vector_type(8)));
typedef float floatx4 __attribute__((ext_vector_type(4)));
typedef unsigned short ushortx8 __attribute__((ext_vector_type(8)));
typedef unsigned short ushortx4 __attribute__((ext_vector_type(4)));

__device__ __forceinline__ unsigned short f2bf(float f) {
  union { float f; unsigned int u; } v;
  v.f = f;
  unsigned int r = v.u + 0x7FFFu + ((v.u >> 16) & 1u);
  return (unsigned short)(r >> 16);
}
__device__ __forceinline__ float bf2f(unsigned short u) {
  union { unsigned int u; float f; } v;
  v.u = ((unsigned int)u) << 16;
  return v.f;
}
__device__ __forceinline__ void gload_lds16(const void* g, void* l) {
  __builtin_amdgcn_global_load_lds((const __attribute__((address_space(1))) void*)g,
                                   (__attribute__((address_space(3))) void*)l, 16, 0, 0);
}

// ---------------------------------------------------------------------------
// 32x128 transpose+cast strip (4 k-tiles): in fp32 [K,N] -> out bf16 [N,K].
// ---------------------------------------------------------------------------
__device__ __forceinline__ void strip_tc(const float* __restrict__ in,
                                         unsigned short* __restrict__ out,
                                         int K, int N, int n0, int k0) {
  __shared__ float tile[4][32][33];
  int t = threadIdx.x;
  int tx = t & 31, ty = t >> 5;
#pragma unroll
  for (int s = 0; s < 4; s++)
#pragma unroll
    for (int r0 = 0; r0 < 4; r0++) {
      int r = ty + r0 * 8;
      tile[s][r][tx] = in[(size_t)(k0 + s * 32 + r) * N + n0 + tx];
    }
  __syncthreads();
  int nr = t >> 3, kq = t & 7;
#pragma unroll
  for (int s = 0; s < 4; s++) {
    ushortx4 o4;
#pragma unroll
    for (int j = 0; j < 4; j++) o4[j] = f2bf(tile[s][kq * 4 + j][nr]);
    *(ushortx4*)(out + (size_t)(n0 + nr) * K + k0 + s * 32 + kq * 4) = o4;
  }
}

// ---------------------------------------------------------------------------
// RMSNorm row -> bf16
// ---------------------------------------------------------------------------
__device__ __forceinline__ void rmsnorm_row(const float* __restrict__ x,
                                            const float* __restrict__ w,
                                            unsigned short* __restrict__ o, int row) {
  __shared__ float red[4];
  int t = threadIdx.x;
  const float* xr = x + (size_t)row * D_;
  float4 xv = *(const float4*)(xr + t * 4);
  float ss = xv.x * xv.x + xv.y * xv.y + xv.z * xv.z + xv.w * xv.w;
#pragma unroll
  for (int off = 32; off >= 1; off >>= 1) ss += __shfl_xor(ss, off);
  if ((t & 63) == 0) red[t >> 6] = ss;
  __syncthreads();
  float total = red[0] + red[1] + red[2] + red[3];
  float r = rsqrtf(total * (1.0f / (float)D_) + EPS_);
  float4 wv = *(const float4*)(w + t * 4);
  unsigned short* op = o + (size_t)row * D_ + t * 4;
  op[0] = f2bf(xv.x * r * wv.x);
  op[1] = f2bf(xv.y * r * wv.y);
  op[2] = f2bf(xv.z * r * wv.z);
  op[3] = f2bf(xv.w * r * wv.w);
}

// ---------------------------------------------------------------------------
// prep_all: 7 weight transposes as 3712 4-tile strips + rmsnorm1 (4096 rows)
// ---------------------------------------------------------------------------
__global__ __launch_bounds__(256) void prep_all(
    const float* __restrict__ wq, const float* __restrict__ wk,
    const float* __restrict__ wv, const float* __restrict__ wo,
    const float* __restrict__ wg, const float* __restrict__ wu,
    const float* __restrict__ wd, unsigned short* __restrict__ wT,
    const float* __restrict__ x, const float* __restrict__ ln1w,
    unsigned short* __restrict__ h_bf) {
  int bid = blockIdx.x;
  if (bid < 3712) {
    const float* in;
    unsigned short* out;
    int K, N, nt, base;
    if (bid < 256)       { in = wq; out = wT;            K = 1024; N = 1024; nt = 32;  base = 0; }
    else if (bid < 320)  { in = wk; out = wT + 1048576;  K = 1024; N = 256;  nt = 8;   base = 256; }
    else if (bid < 384)  { in = wv; out = wT + 1310720;  K = 1024; N = 256;  nt = 8;   base = 320; }
    else if (bid < 640)  { in = wo; out = wT + 1572864;  K = 1024; N = 1024; nt = 32;  base = 384; }
    else if (bid < 1664) { in = wg; out = wT + 2621440;  K = 1024; N = 4096; nt = 128; base = 640; }
    else if (bid < 2688) { in = wu; out = wT + 6815744;  K = 1024; N = 4096; nt = 128; base = 1664; }
    else                 { in = wd; out = wT + 11010048; K = 4096; N = 1024; nt = 32;  base = 2688; }
    int idx = bid - base;
    strip_tc(in, out, K, N, (idx % nt) * 32, (idx / nt) * 128);
  } else {
    rmsnorm_row(x, ln1w, h_bf, bid - 3712);
  }
}

__global__ __launch_bounds__(256) void rmsnorm_bf16_kernel(const float* __restrict__ x,
                                                           const float* __restrict__ w,
                                                           unsigned short* __restrict__ o) {
  rmsnorm_row(x, w, o, blockIdx.x);
}

// ---------------------------------------------------------------------------
// bf16 MFMA GEMM, BK = 32*KH, XOR-swizzled conflict-free LDS.
// Tile = 64 x 128 (MW=32), 2x2 waves.
// EPI: 1 = C=v+R fp32; 2 = C=v+C in-place fp32.  K % (32*KH) == 0.
// ---------------------------------------------------------------------------
template <int EPI, int KH>
__global__ __launch_bounds__(256, 3) void gemm_bf16(const unsigned short* __restrict__ A,
                                                    const unsigned short* __restrict__ BT,
                                                    const float* __restrict__ R,
                                                    float* __restrict__ C,
                                                    int M, int N, int K) {
  __shared__ unsigned short As[KH][64 * 32];
  __shared__ unsigned short Bs[KH][128 * 32];
  int t = threadIdx.x;
  int lane = t & 63, wave = t >> 6;
  int m0 = blockIdx.y * 64, n0 = blockIdx.x * 128;

  int row_a = t >> 2;
  int kc = ((t & 3) ^ ((t >> 3) & 3)) * 8;
  const unsigned short* ga0 = A + (size_t)(m0 + row_a) * K + kc;
  const unsigned short* gb0 = BT + (size_t)(n0 + row_a) * K + kc;
  const unsigned short* gb1 = BT + (size_t)(n0 + 64 + row_a) * K + kc;

  int wm = (wave & 1) * 32, wn = (wave >> 1) * 64;
  int fr = lane & 15, quad = lane >> 4;
  int sw = (quad ^ ((fr >> 1) & 3)) * 8;

  floatx4 acc[2][4];
#pragma unroll
  for (int i = 0; i < 2; i++)
#pragma unroll
    for (int j = 0; j < 4; j++) acc[i][j] = (floatx4){0.f, 0.f, 0.f, 0.f};

  for (int k0 = 0; k0 < K; k0 += 32 * KH) {
#pragma unroll
    for (int h = 0; h < KH; h++) {
      int ko = k0 + h * 32;
      gload_lds16(ga0 + ko, As[h] + wave * 512);
      gload_lds16(gb0 + ko, Bs[h] + wave * 512);
      gload_lds16(gb1 + ko, Bs[h] + 2048 + wave * 512);
    }
    __syncthreads();
#pragma unroll
    for (int h = 0; h < KH; h++) {
      const unsigned short* arp = As[h] + (size_t)(wm + fr) * 32 + sw;
      const unsigned short* brp = Bs[h] + (size_t)(wn + fr) * 32 + sw;
      bf16x8 af[2], bfr[4];
#pragma unroll
      for (int i = 0; i < 2; i++)
        af[i] = __builtin_bit_cast(bf16x8, *(const ushortx8*)(arp + i * 16 * 32));
#pragma unroll
      for (int j = 0; j < 4; j++)
        bfr[j] = __builtin_bit_cast(bf16x8, *(const ushortx8*)(brp + j * 16 * 32));
#pragma unroll
      for (int i = 0; i < 2; i++)
#pragma unroll
        for (int j = 0; j < 4; j++)
          acc[i][j] = __builtin_amdgcn_mfma_f32_16x16x32_bf16(af[i], bfr[j], acc[i][j], 0, 0, 0);
    }
    __syncthreads();
  }

  int orow = m0 + wm + quad * 4;
  int ocol = n0 + wn + fr;
#pragma unroll
  for (int i = 0; i < 2; i++) {
#pragma unroll
    for (int r = 0; r < 4; r++) {
      int row = orow + i * 16 + r;
#pragma unroll
      for (int j = 0; j < 4; j++) {
        size_t idx = (size_t)row * N + ocol + j * 16;
        float v = acc[i][j][r];
        if (EPI == 1) C[idx] = v + R[idx];
        else C[idx] = v + C[idx];
      }
    }
  }
}

// ---------------------------------------------------------------------------
// QKV GEMM with fused rope/transpose epilogue.  Tile 64x128, BK=128 (KH=4).
// bx 0-7 = Q heads (rope+scale -> qb), bx 8-9 = K (rope -> Kb swizzled),
// bx 10-11 = V (transpose -> Vt swizzled).
// ---------------------------------------------------------------------------
__global__ __launch_bounds__(256) void gemm_qkv(const unsigned short* __restrict__ A,
                                                const unsigned short* __restrict__ BT,
                                                unsigned short* __restrict__ qb,
                                                unsigned short* __restrict__ Kb,
                                                unsigned short* __restrict__ Vt) {
  constexpr int K = 1024;
  __shared__ unsigned short smem[24576];  // As4 @0, Bs4 @8192; scratch 64x136 @0
  int t = threadIdx.x;
  int lane = t & 63, wave = t >> 6;
  int bx = blockIdx.x;
  int m0 = blockIdx.y * 64, n0 = bx * 128;

  int row_a = t >> 2;
  int kc = ((t & 3) ^ ((t >> 3) & 3)) * 8;
  const unsigned short* ga0 = A + (size_t)(m0 + row_a) * K + kc;
  const unsigned short* gb0 = BT + (size_t)(n0 + row_a) * K + kc;
  const unsigned short* gb1 = BT + (size_t)(n0 + 64 + row_a) * K + kc;

  int wm = (wave & 1) * 32, wn = (wave >> 1) * 64;
  int fr = lane & 15, quad = lane >> 4;
  int sw = (quad ^ ((fr >> 1) & 3)) * 8;

  floatx4 acc[2][4];
#pragma unroll
  for (int i = 0; i < 2; i++)
#pragma unroll
    for (int j = 0; j < 4; j++) acc[i][j] = (floatx4){0.f, 0.f, 0.f, 0.f};

  for (int k0 = 0; k0 < K; k0 += 128) {
#pragma unroll
    for (int h = 0; h < 4; h++) {
      int ko = k0 + h * 32;
      gload_lds16(ga0 + ko, smem + h * 2048 + wave * 512);
      gload_lds16(gb0 + ko, smem + 8192 + h * 4096 + wave * 512);
      gload_lds16(gb1 + ko, smem + 8192 + h * 4096 + 2048 + wave * 512);
    }
    __syncthreads();
#pragma unroll
    for (int h = 0; h < 4; h++) {
      const unsigned short* arp = smem + h * 2048 + (size_t)(wm + fr) * 32 + sw;
      const unsigned short* brp = smem + 8192 + h * 4096 + (size_t)(wn + fr) * 32 + sw;
      bf16x8 af[2], bfr[4];
#pragma unroll
      for (int i = 0; i < 2; i++)
        af[i] = __builtin_bit_cast(bf16x8, *(const ushortx8*)(arp + i * 16 * 32));
#pragma unroll
      for (int j = 0; j < 4; j++)
        bfr[j] = __builtin_bit_cast(bf16x8, *(const ushortx8*)(brp + j * 16 * 32));
#pragma unroll
      for (int i = 0; i < 2; i++)
#pragma unroll
        for (int j = 0; j < 4; j++)
          acc[i][j] = __builtin_amdgcn_mfma_f32_16x16x32_bf16(af[i], bfr[j], acc[i][j], 0, 0, 0);
    }
    __syncthreads();
  }

  unsigned short* scr = smem;
#pragma unroll
  for (int i = 0; i < 2; i++)
#pragma unroll
    for (int r = 0; r < 4; r++)
#pragma unroll
      for (int j = 0; j < 4; j++)
        scr[(size_t)(wm + quad * 4 + i * 16 + r) * 136 + wn + fr + j * 16] =
            f2bf(acc[i][j][r]);
  __syncthreads();

  if (bx < 10) {
    int row = t >> 2, dq = (t & 3) * 16;
    int tok = m0 + row, pos = tok & (L_ - 1), b = tok >> 11;
    float scale_ = (bx < 8) ? 0.08838834764831843f : 1.0f;
    unsigned short lo[16], hi[16];
#pragma unroll
    for (int m = 0; m < 16; m++) {
      int d2 = dq + m;
      float x1 = bf2f(scr[(size_t)row * 136 + d2]);
      float x2 = bf2f(scr[(size_t)row * 136 + d2 + 64]);
      float inv_ts = expf(-0.14391156831f * (float)d2);
      float rad = (float)pos * inv_ts;
      float s = sinf(rad), c = cosf(rad);
      lo[m] = f2bf((x1 * c - x2 * s) * scale_);
      hi[m] = f2bf((x2 * c + x1 * s) * scale_);
    }
    if (bx < 8) {
      unsigned short* dst = qb + (size_t)tok * 1024 + bx * 128;
      *(ushortx8*)(dst + dq) = *(const ushortx8*)(lo);
      *(ushortx8*)(dst + dq + 8) = *(const ushortx8*)(lo + 8);
      *(ushortx8*)(dst + 64 + dq) = *(const ushortx8*)(hi);
      *(ushortx8*)(dst + 64 + dq + 8) = *(const ushortx8*)(hi + 8);
    } else {
      int kvh = bx - 8, bk = b * KVH_ + kvh, swk = pos & 15;
      unsigned short* dst = Kb + ((size_t)bk * L_ + pos) * HD_;
      int c0 = dq >> 3;
      *(ushortx8*)(dst + ((c0) ^ swk) * 8) = *(const ushortx8*)(lo);
      *(ushortx8*)(dst + ((c0 + 1) ^ swk) * 8) = *(const ushortx8*)(lo + 8);
      *(ushortx8*)(dst + ((c0 + 8) ^ swk) * 8) = *(const ushortx8*)(hi);
      *(ushortx8*)(dst + ((c0 + 9) ^ swk) * 8) = *(const ushortx8*)(hi + 8);
    }
  } else {
    int kvh = bx - 10;
    int b = m0 >> 11, key0 = m0 & (L_ - 1), bk = b * KVH_ + kvh;
    int hd = t >> 1, half = t & 1;
#pragma unroll
    for (int c = 0; c < 4; c++) {
      int cp = half * 4 + c, kcc = cp ^ (hd & 7);
      ushortx8 ob;
#pragma unroll
      for (int j = 0; j < 8; j++) ob[j] = scr[(size_t)(kcc * 8 + j) * 136 + hd];
      *(ushortx8*)(Vt + ((size_t)bk * HD_ + hd) * L_ + key0 + cp * 8) = ob;
    }
  }
}

// ---------------------------------------------------------------------------
// Fused gate+up GEMM, tile 128M x 64N (waves stack on M), BK=64.
// ---------------------------------------------------------------------------
__global__ __launch_bounds__(256, 3) void gemm_gateup(const unsigned short* __restrict__ A,
                                                      const unsigned short* __restrict__ BgT,
                                                      const unsigned short* __restrict__ BuT,
                                                      unsigned short* __restrict__ Cb,
                                                      int M, int K) {
  constexpr int N = FFN_;
  __shared__ unsigned short As[2][128 * 32];
  __shared__ unsigned short Bgs[2][64 * 32];
  __shared__ unsigned short Bus[2][64 * 32];
  int t = threadIdx.x;
  int lane = t & 63, wave = t >> 6;
  int m0 = blockIdx.y * 128, n0 = blockIdx.x * 64;

  int row_a = t >> 2;
  int kc = ((t & 3) ^ ((t >> 3) & 3)) * 8;
  const unsigned short* ga0 = A + (size_t)(m0 + row_a) * K + kc;
  const unsigned short* ga1 = A + (size_t)(m0 + 64 + row_a) * K + kc;
  const unsigned short* gg0 = BgT + (size_t)(n0 + row_a) * K + kc;
  const unsigned short* gu0 = BuT + (size_t)(n0 + row_a) * K + kc;

  int wm = wave * 32;
  int fr = lane & 15, quad = lane >> 4;
  int sw = (quad ^ ((fr >> 1) & 3)) * 8;

  floatx4 accg[2][4], accu[2][4];
#pragma unroll
  for (int i = 0; i < 2; i++)
#pragma unroll
    for (int j = 0; j < 4; j++) {
      accg[i][j] = (floatx4){0.f, 0.f, 0.f, 0.f};
      accu[i][j] = (floatx4){0.f, 0.f, 0.f, 0.f};
    }

  for (int k0 = 0; k0 < K; k0 += 64) {
#pragma unroll
    for (int h = 0; h < 2; h++) {
      int ko = k0 + h * 32;
      gload_lds16(ga0 + ko, As[h] + wave * 512);
      gload_lds16(ga1 + ko, As[h] + 2048 + wave * 512);
      gload_lds16(gg0 + ko, Bgs[h] + wave * 512);
      gload_lds16(gu0 + ko, Bus[h] + wave * 512);
    }
    __syncthreads();
#pragma unroll
    for (int h = 0; h < 2; h++) {
      const unsigned short* arp = As[h] + (size_t)(wm + fr) * 32 + sw;
      const unsigned short* grp = Bgs[h] + (size_t)fr * 32 + sw;
      const unsigned short* urp = Bus[h] + (size_t)fr * 32 + sw;
      bf16x8 af[2], bg[4], bu[4];
#pragma unroll
      for (int i = 0; i < 2; i++)
        af[i] = __builtin_bit_cast(bf16x8, *(const ushortx8*)(arp + i * 16 * 32));
#pragma unroll
      for (int j = 0; j < 4; j++) {
        bg[j] = __builtin_bit_cast(bf16x8, *(const ushortx8*)(grp + j * 16 * 32));
        bu[j] = __builtin_bit_cast(bf16x8, *(const ushortx8*)(urp + j * 16 * 32));
      }
#pragma unroll
      for (int i = 0; i < 2; i++)
#pragma unroll
        for (int j = 0; j < 4; j++) {
          accg[i][j] = __builtin_amdgcn_mfma_f32_16x16x32_bf16(af[i], bg[j], accg[i][j], 0, 0, 0);
          accu[i][j] = __builtin_amdgcn_mfma_f32_16x16x32_bf16(af[i], bu[j], accu[i][j], 0, 0, 0);
        }
    }
    __syncthreads();
  }

  int orow = m0 + wm + quad * 4;
  int ocol = n0 + fr;
#pragma unroll
  for (int i = 0; i < 2; i++) {
#pragma unroll
    for (int r = 0; r < 4; r++) {
      int row = orow + i * 16 + r;
#pragma unroll
      for (int j = 0; j < 4; j++) {
        float g = accg[i][j][r];
        float u = accu[i][j][r];
        Cb[(size_t)row * N + ocol + j * 16] = f2bf(g / (1.f + __expf(-g)) * u);
      }
    }
  }
}

// ---------------------------------------------------------------------------
// MFMA flash attention, no-max softmax, Q pre-roped.  K/V staging is
// DOUBLE-BUFFERED: tile kt+1 is issued (async global_load_lds, no wait)
// right after the barrier, compute runs on tile kt, so the vmcnt drain at
// the next barrier lands a full tile of compute later.  1 barrier/tile.
// ---------------------------------------------------------------------------
__global__ __launch_bounds__(256) void attn_mfma(const unsigned short* __restrict__ qb,
                                                 const unsigned short* __restrict__ Kb,
                                                 const unsigned short* __restrict__ Vt,
                                                 unsigned short* __restrict__ ctx) {
  __shared__ unsigned short Ks[2][64 * 128];
  __shared__ unsigned short Vs[2][128 * 64];
  __shared__ unsigned short Ps[4][16 * 72];
  int id = blockIdx.x;
  int bh = id & 15;
  int p_ = id >> 4;
  int qt = (p_ < 16) ? p_ : 47 - p_;
  int b = bh >> 3, h = bh & 7;
  int bk = b * KVH_ + (h >> 2);
  int q0 = qt * 64;
  int t = threadIdx.x, lane = t & 63, w = t >> 6;
  int fr = lane & 15, quad = lane >> 4;

  int pos = q0 + w * 16 + fr;
  const unsigned short* qrow = qb + (size_t)(b * L_ + pos) * 1024 + h * HD_;
  bf16x8 qf[4];
#pragma unroll
  for (int kb = 0; kb < 4; kb++)
    qf[kb] = __builtin_bit_cast(bf16x8, *(const ushortx8*)(qrow + kb * 32 + quad * 8));

  floatx4 o_acc[8];
#pragma unroll
  for (int nt = 0; nt < 8; nt++) o_acc[nt] = (floatx4){0.f, 0.f, 0.f, 0.f};
  float l_r[4] = {0.f, 0.f, 0.f, 0.f};
  unsigned short* Psw = Ps[w];
  const unsigned short* kgb = Kb + (size_t)bk * L_ * HD_;
  const unsigned short* vgb = Vt + (size_t)bk * HD_ * L_;
  int rowg0 = q0 + w * 16 + quad * 4;

  // prologue: stage tile 0 into buffer 0
  {
    const unsigned short* ksrc = kgb;
#pragma unroll
    for (int it = 0; it < 4; it++) {
      int sl = it * 4 + w;
      gload_lds16(ksrc + sl * 512 + lane * 8, Ks[0] + sl * 512);
      gload_lds16(vgb + (size_t)(sl * 8 + (lane >> 3)) * L_ + (lane & 7) * 8,
                  Vs[0] + sl * 512);
    }
  }

  for (int kt = 0; kt <= qt; kt++) {
    int buf = kt & 1;
    int kstart = kt * 64;
    bool diag = (kt == qt);
    __syncthreads();  // drains this wave's staging of buf; all waves done reading buf^1
    if (!diag) {
      int knext = kstart + 64;
      const unsigned short* ksrc = kgb + (size_t)knext * HD_;
#pragma unroll
      for (int it = 0; it < 4; it++) {
        int sl = it * 4 + w;
        gload_lds16(ksrc + sl * 512 + lane * 8, Ks[buf ^ 1] + sl * 512);
        gload_lds16(vgb + (size_t)(sl * 8 + (lane >> 3)) * L_ + knext + (lane & 7) * 8,
                    Vs[buf ^ 1] + sl * 512);
      }
    }

    floatx4 s_acc[4];
#pragma unroll
    for (int jt = 0; jt < 4; jt++) s_acc[jt] = (floatx4){0.f, 0.f, 0.f, 0.f};
#pragma unroll
    for (int kb = 0; kb < 4; kb++) {
#pragma unroll
      for (int jt = 0; jt < 4; jt++) {
        bf16x8 kf = __builtin_bit_cast(
            bf16x8, *(const ushortx8*)(Ks[buf] + (jt * 16 + fr) * 128 +
                                       (((kb * 4 + quad) ^ fr) * 8)));
        s_acc[jt] = __builtin_amdgcn_mfma_f32_16x16x32_bf16(qf[kb], kf, s_acc[jt], 0, 0, 0);
      }
    }

#pragma unroll
    for (int jt = 0; jt < 4; jt++) {
#pragma unroll
      for (int r = 0; r < 4; r++) {
        float pp;
        if (diag) {
          int keyg = kstart + jt * 16 + fr;
          pp = (keyg <= rowg0 + r) ? __expf(s_acc[jt][r]) : 0.f;
        } else {
          pp = __expf(s_acc[jt][r]);
        }
        l_r[r] += pp;
        Psw[(quad * 4 + r) * 72 + jt * 16 + fr] = f2bf(pp);
      }
    }
    bf16x8 pf0 = __builtin_bit_cast(bf16x8, *(const ushortx8*)(Psw + fr * 72 + quad * 8));
    bf16x8 pf1 =
        __builtin_bit_cast(bf16x8, *(const ushortx8*)(Psw + fr * 72 + 32 + quad * 8));
#pragma unroll
    for (int nt = 0; nt < 8; nt++) {
      bf16x8 vf0 = __builtin_bit_cast(
          bf16x8,
          *(const ushortx8*)(Vs[buf] + (nt * 16 + fr) * 64 + ((quad ^ (fr & 7)) * 8)));
      bf16x8 vf1 = __builtin_bit_cast(
          bf16x8,
          *(const ushortx8*)(Vs[buf] + (nt * 16 + fr) * 64 + (((4 + quad) ^ (fr & 7)) * 8)));
      o_acc[nt] = __builtin_amdgcn_mfma_f32_16x16x32_bf16(pf0, vf0, o_acc[nt], 0, 0, 0);
      o_acc[nt] = __builtin_amdgcn_mfma_f32_16x16x32_bf16(pf1, vf1, o_acc[nt], 0, 0, 0);
    }
  }

#pragma unroll
  for (int r = 0; r < 4; r++) {
    l_r[r] += __shfl_xor(l_r[r], 1);
    l_r[r] += __shfl_xor(l_r[r], 2);
    l_r[r] += __shfl_xor(l_r[r], 4);
    l_r[r] += __shfl_xor(l_r[r], 8);
  }

  unsigned short* ob =
      ctx + (size_t)(b * L_ + q0 + w * 16 + quad * 4) * 1024 + h * HD_ + fr;
#pragma unroll
  for (int r = 0; r < 4; r++) {
    float inv = 1.f / l_r[r];
    unsigned short* orow = ob + (size_t)r * 1024;
#pragma unroll
    for (int nt = 0; nt < 8; nt++) orow[nt * 16] = f2bf(o_acc[nt][r] * inv);
  }
}

// ---------------------------------------------------------------------------
extern "C" void kernel_launch(void* const* d_in, const int* in_sizes, int n_in,
                              void* d_out, int out_size, void* d_ws, size_t ws_size,
                              hipStream_t stream) {
  const float* x    = (const float*)d_in[0];
  const float* ln1w = (const float*)d_in[1];
  const float* wq   = (const float*)d_in[2];
  const float* wk   = (const float*)d_in[3];
  const float* wvp  = (const float*)d_in[4];
  const float* wo   = (const float*)d_in[5];
  const float* ln2w = (const float*)d_in[6];
  const float* wg   = (const float*)d_in[7];
  const float* wu   = (const float*)d_in[8];
  const float* wd   = (const float*)d_in[9];
  float* out = (float*)d_out;
  char* ws = (char*)d_ws;

  // workspace layout (bytes), ~91 MB total:
  unsigned short* wT = (unsigned short*)ws;                       // 30,408,704 B
  unsigned short* wqkvT = wT;                                     // [1536][1024]
  unsigned short* woT = wT + 1572864;                             // [1024][1024]
  unsigned short* wgT = wT + 2621440;                             // [4096][1024]
  unsigned short* wuT = wT + 6815744;                             // [4096][1024]
  unsigned short* wdT = wT + 11010048;                            // [1024][4096]
  unsigned short* h_bf = (unsigned short*)(ws + 30408704);        // 8 MB (ctx_bf reuse)
  unsigned short* qb = (unsigned short*)(ws + 38797312);          // [4096][1024] roped Q, 8 MB
  unsigned short* h2_bf = (unsigned short*)(ws + 51380224);       // 8 MB
  unsigned short* Kb = (unsigned short*)(ws + 59768832);          // 2 MB (attn phase)
  unsigned short* Vt = (unsigned short*)(ws + 61865984);          // 2 MB (attn phase)
  unsigned short* gu = (unsigned short*)(ws + 59768832);          // 32 MB (FFN phase)
  unsigned short* ctx_bf = h_bf;

  dim3 blk(256);

  // 1. weight transposes (4-tile strips) + rmsnorm1
  prep_all<<<3712 + T_, blk, 0, stream>>>(wq, wk, wvp, wo, wg, wu, wd, wT, x, ln1w, h_bf);
  // 2. fused QKV GEMM (BK=128) + rope(Q,K) + V transpose
  gemm_qkv<<<dim3(12, 64), blk, 0, stream>>>(h_bf, wqkvT, qb, Kb, Vt);
  // 3. attention (no-max softmax, Q pre-roped, double-buffered K/V)
  attn_mfma<<<512, blk, 0, stream>>>(qb, Kb, Vt, ctx_bf);
  // 4. out = ctx @ wo + x   (BK=128)
  gemm_bf16<1, 4><<<dim3(8, 64), blk, 0, stream>>>(ctx_bf, woT, x, out, T_, 1024, 1024);
  // 5. rmsnorm2 on out
  rmsnorm_bf16_kernel<<<T_, blk, 0, stream>>>(out, ln2w, h2_bf);
  // 6. gate+up fused, tile 128x64
  gemm_gateup<<<dim3(64, 32), blk, 0, stream>>>(h2_bf, wgT, wuT, gu, T_, 1024);
  // 7. out += gu @ wd (in-place residual accumulate, BK=128)
  gemm_bf16<2, 4><<<dim3(8, 64), blk, 0, stream>>>(gu, wdT, nullptr, out, T_, 1024, FFN_);
}